// Round 11
// baseline (321.325 us; speedup 1.0000x reference)
//
#include <hip/hip_runtime.h>
#include <hip/hip_bf16.h>

#define NN 50000
#define NE 500000
#define F 128
#define K_IN 128
#define ED 64
#define C 2
#define NEG 0.2f
#define FLTMAX 3.402823466e38f

typedef __attribute__((ext_vector_type(8))) short short8;
typedef __attribute__((ext_vector_type(4))) float f32x4;

#define FMA4(acc, v, s) do { \
    acc[0] = fmaf((v)[0], (s), acc[0]); \
    acc[1] = fmaf((v)[1], (s), acc[1]); \
    acc[2] = fmaf((v)[2], (s), acc[2]); \
    acc[3] = fmaf((v)[3], (s), acc[3]); } while (0)

__device__ __forceinline__ short bf16r(float f) {
    unsigned u = __float_as_uint(f);
    unsigned r = (u + 0x7fffu + ((u >> 16) & 1u)) >> 16;
    return (short)r;
}

__device__ __forceinline__ short8 ldfrag(const float* base) {
    const float4* p = reinterpret_cast<const float4*>(base);
    float4 v0 = p[0], v1 = p[1];
    short8 r;
    r[0] = bf16r(v0.x); r[1] = bf16r(v0.y); r[2] = bf16r(v0.z); r[3] = bf16r(v0.w);
    r[4] = bf16r(v1.x); r[5] = bf16r(v1.y); r[6] = bf16r(v1.z); r[7] = bf16r(v1.w);
    return r;
}

__device__ __forceinline__ short8 cvt8(float4 v0, float4 v1) {
    short8 r;
    r[0] = bf16r(v0.x); r[1] = bf16r(v0.y); r[2] = bf16r(v0.z); r[3] = bf16r(v0.w);
    r[4] = bf16r(v1.x); r[5] = bf16r(v1.y); r[6] = bf16r(v1.z); r[7] = bf16r(v1.w);
    return r;
}

// ---------------- projection via MFMA: xb = x @ W_l^T ----------------
__global__ __launch_bounds__(256) void proj_mfma(const float* __restrict__ x,
                                                 const float* __restrict__ W_l,
                                                 float* __restrict__ xb) {
    int lane = threadIdx.x & 63, wid = threadIdx.x >> 6;
    int grp = lane >> 4, col = lane & 15;
    int tile = blockIdx.x * 4 + wid;
    if (tile >= NN / 16) return;
    int n0 = tile * 16;

    f32x4 acc[8];
#pragma unroll
    for (int t = 0; t < 8; ++t) acc[t] = (f32x4){0.f, 0.f, 0.f, 0.f};

    const float* arow = x + (size_t)(n0 + col) * K_IN + grp * 8;
#pragma unroll
    for (int kt = 0; kt < 4; ++kt) {
        short8 a = ldfrag(arow + kt * 32);
#pragma unroll
        for (int t = 0; t < 8; ++t) {
            short8 b = ldfrag(W_l + (size_t)(t * 16 + col) * K_IN + kt * 32 + grp * 8);
            acc[t] = __builtin_amdgcn_mfma_f32_16x16x32_bf16(a, b, acc[t], 0, 0, 0);
        }
    }
#pragma unroll
    for (int j = 0; j < 4; ++j) {
        float* orow = xb + (size_t)(n0 + grp * 4 + j) * F + col;
#pragma unroll
        for (int t = 0; t < 8; ++t) orow[t * 16] = acc[t][j];
    }
}

// ---------------- CSR build ----------------
__global__ void hist_kernel(const int* __restrict__ ei, int* __restrict__ counts) {
    int e = blockIdx.x * blockDim.x + threadIdx.x;
    if (e < NE) atomicAdd(&counts[ei[NE + e]], 1);
}

__global__ __launch_bounds__(1024) void scan1_kernel(const int* __restrict__ counts,
                                                     int* __restrict__ offs,
                                                     int* __restrict__ bsum) {
    __shared__ int wsum[16];
    int i = blockIdx.x * 1024 + threadIdx.x;
    int lane = threadIdx.x & 63, w = threadIdx.x >> 6;
    int v = (i < NN) ? counts[i] : 0;
    int x = v;
#pragma unroll
    for (int off = 1; off < 64; off <<= 1) {
        int y = __shfl_up(x, off, 64);
        if (lane >= off) x += y;
    }
    if (lane == 63) wsum[w] = x;
    __syncthreads();
    if (w == 0 && lane < 16) {
        int t = wsum[lane];
#pragma unroll
        for (int off = 1; off < 16; off <<= 1) {
            int y = __shfl_up(t, off, 16);
            if (lane >= off) t += y;
        }
        wsum[lane] = t;
    }
    __syncthreads();
    int woff = (w == 0) ? 0 : wsum[w - 1];
    if (i < NN) offs[i] = woff + x - v;
    if (threadIdx.x == 1023) bsum[blockIdx.x] = woff + x;
}

__global__ void scan2_kernel(int* __restrict__ bsum, int nb) {
    int tid = threadIdx.x;
    int v = (tid < nb) ? bsum[tid] : 0;
    int x = v;
#pragma unroll
    for (int off = 1; off < 64; off <<= 1) {
        int y = __shfl_up(x, off, 64);
        if (tid >= off) x += y;
    }
    if (tid < nb) bsum[tid] = x - v;
}

__global__ __launch_bounds__(1024) void scan3_kernel(int* __restrict__ offs,
                                                     const int* __restrict__ bsum,
                                                     int* __restrict__ cursor) {
    int i = blockIdx.x * 1024 + threadIdx.x;
    if (i < NN) {
        int o = offs[i] + bsum[blockIdx.x];
        offs[i] = o;
        cursor[i] = o;
    }
    if (i == 0) offs[NN] = NE;
}

// perm2[p] = {edge, src}; tgts[p] = tgt
__global__ void scatter_kernel(const int* __restrict__ ei, int* __restrict__ cursor,
                               int2* __restrict__ perm2, int* __restrict__ tgts) {
    int e = blockIdx.x * blockDim.x + threadIdx.x;
    if (e < NE) {
        int src = ei[e];
        int tgt = ei[NE + e];
        int p = atomicAdd(&cursor[tgt], 1);
        int2 v; v.x = e; v.y = src;
        perm2[p] = v;
        tgts[p] = tgt;
    }
}

// ---------------- edge logits, sorted order, software-pipelined ----------------
// metadata prefetched 2 iterations ahead; ea row raw-floats 1 iteration ahead.
template<bool WMSG>
__global__ __launch_bounds__(256) void edge_logits_mfma(
    const int2* __restrict__ perm2, const int* __restrict__ tgts,
    const float* __restrict__ ea,
    const float* __restrict__ xb, const float* __restrict__ W_e,
    const float* __restrict__ cb, const float* __restrict__ att,
    const float* __restrict__ att_sc, const float* __restrict__ ebias,
    float* __restrict__ lgs, unsigned short* __restrict__ msg) {
    int lane = threadIdx.x & 63, wid = threadIdx.x >> 6;
    int grp = lane >> 4, col = lane & 15;

    short8 B[8][2];
#pragma unroll
    for (int t = 0; t < 8; ++t)
#pragma unroll
        for (int kt = 0; kt < 2; ++kt)
            B[t][kt] = ldfrag(W_e + (size_t)(t * 16 + col) * ED + kt * 32 + grp * 8);

    float attv[8], cbe0[8], cbe1[8];
#pragma unroll
    for (int t = 0; t < 8; ++t) {
        int f = t * 16 + col;
        attv[t] = att[f];
        cbe0[t] = cb[f] + ebias[f * 2];
        cbe1[t] = cb[F + f] + ebias[f * 2 + 1];
    }
    float as0 = att_sc[0], as1 = att_sc[1];
    float2* lgs2 = reinterpret_cast<float2*>(lgs);

    const int NT = NE / 16;
    const int stride = gridDim.x * 4;
    int tile = blockIdx.x * 4 + wid;

    // pipeline state
    int2 pe0 = {0, 0}, pe1 = {0, 0};
    int tg0 = 0, tg1 = 0;
    float4 rc0, rc1, rc2, rc3;   // raw ea floats for CURRENT tile

    if (tile < NT) {
        pe0 = perm2[tile * 16 + col];
        tg0 = tgts[tile * 16 + col];
    }
    int tb = tile + stride;
    if (tb < NT) {
        pe1 = perm2[tb * 16 + col];
        tg1 = tgts[tb * 16 + col];
    }
    if (tile < NT) {
        const float* base = ea + (size_t)pe0.x * ED + grp * 8;
        const float4* ap = reinterpret_cast<const float4*>(base);
        rc0 = ap[0]; rc1 = ap[1];
        const float4* ap2 = reinterpret_cast<const float4*>(base + 32);
        rc2 = ap2[0]; rc3 = ap2[1];
    }

    for (; tile < NT; tile += stride) {
        int tn = tile + stride;
        int tnn = tile + 2 * stride;

        // issue next-tile ea raw loads (pe1 resident from 2-ahead prefetch)
        float4 rn0, rn1, rn2, rn3;
        if (tn < NT) {
            const float* base = ea + (size_t)pe1.x * ED + grp * 8;
            const float4* ap = reinterpret_cast<const float4*>(base);
            rn0 = ap[0]; rn1 = ap[1];
            const float4* ap2 = reinterpret_cast<const float4*>(base + 32);
            rn2 = ap2[0]; rn3 = ap2[1];
        }
        // issue metadata 2 ahead
        int2 pe2 = {0, 0}; int tg2 = 0;
        if (tnn < NT) {
            pe2 = perm2[tnn * 16 + col];
            tg2 = tgts[tnn * 16 + col];
        }

        // convert current raw (resident) and compute
        short8 a0 = cvt8(rc0, rc1);
        short8 a1 = cvt8(rc2, rc3);
        f32x4 acc[8];
#pragma unroll
        for (int t = 0; t < 8; ++t) acc[t] = (f32x4){0.f, 0.f, 0.f, 0.f};
#pragma unroll
        for (int t = 0; t < 8; ++t) {
            acc[t] = __builtin_amdgcn_mfma_f32_16x16x32_bf16(a0, B[t][0], acc[t], 0, 0, 0);
            acc[t] = __builtin_amdgcn_mfma_f32_16x16x32_bf16(a1, B[t][1], acc[t], 0, 0, 0);
        }
        int p0 = tile * 16;
        int srcv = pe0.y;
#pragma unroll
        for (int j = 0; j < 4; ++j) {
            int idx = grp * 4 + j;
            int src = __shfl(srcv, idx, 16);
            int tgt = __shfl(tg0, idx, 16);   // ~uniform per tile (sorted)
            const float* xbs = xb + (size_t)src * F + col;
            const float* xbt = xb + (size_t)tgt * F + col;
            float q0 = 0.f, q1 = 0.f;
#pragma unroll
            for (int t = 0; t < 8; ++t) {
                float mv = xbs[t * 16] + acc[t][j];        // xj + emb
                if (WMSG)
                    msg[(size_t)(p0 + idx) * F + t * 16 + col] = (unsigned short)bf16r(mv);
                float s = mv + xbt[t * 16];
                float u0 = s + cbe0[t]; u0 = fmaxf(u0, NEG * u0);
                float u1 = s + cbe1[t]; u1 = fmaxf(u1, NEG * u1);
                q0 = fmaf(u0, attv[t], q0);
                q1 = fmaf(u1, attv[t], q1);
            }
#pragma unroll
            for (int off = 8; off; off >>= 1) {
                q0 += __shfl_xor(q0, off, 16);
                q1 += __shfl_xor(q1, off, 16);
            }
            if (col == 0) {
                float2 o; o.x = q0 * as0; o.y = q1 * as1;
                lgs2[p0 + idx] = o;
            }
        }
        // rotate pipeline
        pe0 = pe1; tg0 = tg1;
        pe1 = pe2; tg1 = tg2;
        rc0 = rn0; rc1 = rn1; rc2 = rn2; rc3 = rn3;
    }
}

// ---------------- streaming aggregation from msg ----------------
__global__ __launch_bounds__(512) void agg_msg(
    const int* __restrict__ offs, const int2* __restrict__ perm2,
    const unsigned short* __restrict__ msg, const float* __restrict__ ebias,
    const float* __restrict__ lgs,
    float* __restrict__ out, float* __restrict__ alpha_out) {
    int lane = threadIdx.x & 63;
    int node = blockIdx.x * 8 + (threadIdx.x >> 6);
    if (node >= NN) return;
    int beg = offs[node], end = offs[node + 1];
    int deg = end - beg;
    float* orow = out + (size_t)node * (C * F);
    float2* orow2 = reinterpret_cast<float2*>(orow);
    if (deg == 0) {
        float2 z; z.x = 0.f; z.y = 0.f;
        orow2[lane] = z; orow2[64 + lane] = z;
        return;
    }
    const float2* lgs2 = reinterpret_cast<const float2*>(lgs);
    float2* al2 = reinterpret_cast<float2*>(alpha_out);

    float m0 = -FLTMAX, m1 = -FLTMAX;
    for (int j = beg + lane; j < end; j += 64) {
        float2 lg = lgs2[j];
        m0 = fmaxf(m0, lg.x); m1 = fmaxf(m1, lg.y);
    }
#pragma unroll
    for (int off = 32; off; off >>= 1) {
        m0 = fmaxf(m0, __shfl_xor(m0, off, 64));
        m1 = fmaxf(m1, __shfl_xor(m1, off, 64));
    }
    float su0 = 0.f, su1 = 0.f;
    for (int j = beg + lane; j < end; j += 64) {
        float2 lg = lgs2[j];
        su0 += __expf(lg.x - m0); su1 += __expf(lg.y - m1);
    }
#pragma unroll
    for (int off = 32; off; off >>= 1) {
        su0 += __shfl_xor(su0, off, 64);
        su1 += __shfl_xor(su1, off, 64);
    }
    float inv0 = 1.f / (su0 + 1e-16f), inv1 = 1.f / (su1 + 1e-16f);

    float g00 = 0.f, g01 = 0.f, g10 = 0.f, g11 = 0.f;
    for (int cb0 = beg; cb0 < end; cb0 += 64) {
        int cnt = min(64, end - cb0);
        int jl = cb0 + min(lane, cnt - 1);
        bool act = lane < cnt;
        int el = perm2[jl].x;
        float2 lgl = lgs2[jl];
        float e0v = act ? __expf(lgl.x - m0) : 0.f;
        float e1v = act ? __expf(lgl.y - m1) : 0.f;
        if (act) { float2 av; av.x = e0v * inv0; av.y = e1v * inv1; al2[el] = av; }
#pragma unroll 4
        for (int i = 0; i < cnt; ++i) {
            float a0 = __shfl(e0v, i, 64) * inv0;
            float a1 = __shfl(e1v, i, 64) * inv1;
            unsigned mv = *reinterpret_cast<const unsigned*>(
                msg + (size_t)(cb0 + i) * F + lane * 2);
            float f0 = __uint_as_float((mv & 0xffffu) << 16);
            float f1 = __uint_as_float(mv & 0xffff0000u);
            g00 = fmaf(a0, f0, g00); g01 = fmaf(a0, f1, g01);
            g10 = fmaf(a1, f0, g10); g11 = fmaf(a1, f1, g11);
        }
    }
    float sa0 = su0 * inv0, sa1 = su1 * inv1;
    int f0i = lane * 2, f1i = lane * 2 + 1;
    float2 r0, r1;
    r0.x = g00 + ebias[f0i * 2] * sa0;
    r0.y = g01 + ebias[f1i * 2] * sa0;
    r1.x = g10 + ebias[f0i * 2 + 1] * sa1;
    r1.y = g11 + ebias[f1i * 2 + 1] * sa1;
    orow2[lane] = r0;
    orow2[64 + lane] = r1;
}

// ---------------- fallback (r6/r9 structure): gather4 agg + H + emb_gemm ----------------
__device__ __forceinline__ void gather4(int cdeg, int el, int sl, float e0v, float e1v,
                                        float inv0, float inv1,
                                        const float* __restrict__ ea,
                                        const float* __restrict__ xb, int lane,
                                        f32x4& h0q, f32x4& h1q, f32x4& g0, f32x4& g1) {
    int quad = lane >> 4, sub16 = lane & 15;
    int half = lane >> 5, sub32 = lane & 31;
    for (int jj = 0; jj < cdeg; jj += 4) {
        int idx = jj + quad;
        int cidx = min(idx, cdeg - 1);
        float w0 = (idx < cdeg) ? inv0 : 0.f;
        float w1 = (idx < cdeg) ? inv1 : 0.f;
        float a0q = __shfl(e0v, cidx, 64) * w0;
        float a1q = __shfl(e1v, cidx, 64) * w1;
        int eq = __shfl(el, cidx, 64);
        f32x4 ev = *reinterpret_cast<const f32x4*>(ea + (size_t)eq * ED + sub16 * 4);
        FMA4(h0q, ev, a0q); FMA4(h1q, ev, a1q);

        int idh = jj + half;
        int ch = min(idh, cdeg - 1);
        float b0 = (idh < cdeg) ? inv0 : 0.f;
        float b1 = (idh < cdeg) ? inv1 : 0.f;
        float aA0 = __shfl(e0v, ch, 64) * b0;
        float aA1 = __shfl(e1v, ch, 64) * b1;
        int sA = __shfl(sl, ch, 64);
        f32x4 xv = *reinterpret_cast<const f32x4*>(xb + (size_t)sA * F + sub32 * 4);
        FMA4(g0, xv, aA0); FMA4(g1, xv, aA1);

        int idh2 = jj + 2 + half;
        int ch2 = min(idh2, cdeg - 1);
        float c0 = (idh2 < cdeg) ? inv0 : 0.f;
        float c1 = (idh2 < cdeg) ? inv1 : 0.f;
        float aB0 = __shfl(e0v, ch2, 64) * c0;
        float aB1 = __shfl(e1v, ch2, 64) * c1;
        int sB = __shfl(sl, ch2, 64);
        f32x4 xv2 = *reinterpret_cast<const f32x4*>(xb + (size_t)sB * F + sub32 * 4);
        FMA4(g0, xv2, aB0); FMA4(g1, xv2, aB1);
    }
}

__global__ __launch_bounds__(512) void agg_fast(
    const int* __restrict__ offs, const int2* __restrict__ perm2,
    const float* __restrict__ ea, const float* __restrict__ xb,
    const float* __restrict__ ebias, const float* __restrict__ lgs,
    float* __restrict__ out, float* __restrict__ alpha_out,
    float* __restrict__ H) {
    int lane = threadIdx.x & 63;
    int node = blockIdx.x * 8 + (threadIdx.x >> 6);
    if (node >= NN) return;
    int beg = offs[node], end = offs[node + 1];
    int deg = end - beg;
    int half = lane >> 5, sub32 = lane & 31;
    float* orow = out + (size_t)node * (C * F);
    float* hrow = H + (size_t)node * (C * ED);

    if (deg == 0) {
        f32x4 z = (f32x4){0.f, 0.f, 0.f, 0.f};
        *reinterpret_cast<f32x4*>(orow + half * F + sub32 * 4) = z;
        if (lane < 32) *reinterpret_cast<f32x4*>(hrow + lane * 4) = z;
        return;
    }
    const float2* lgs2 = reinterpret_cast<const float2*>(lgs);
    float2* al2 = reinterpret_cast<float2*>(alpha_out);

    f32x4 h0q = (f32x4){0.f,0.f,0.f,0.f}, h1q = h0q, gA0 = h0q, gA1 = h0q;
    float s0, s1, inv0, inv1;

    if (deg <= 64) {
        int jl = beg + min(lane, deg - 1);
        int2 pe = perm2[jl];
        int el = pe.x, sl = pe.y;
        float2 lgl = lgs2[jl];
        bool act = lane < deg;
        float l0 = act ? lgl.x : -FLTMAX;
        float l1 = act ? lgl.y : -FLTMAX;
        float m0 = l0, m1 = l1;
#pragma unroll
        for (int off = 32; off; off >>= 1) {
            m0 = fmaxf(m0, __shfl_xor(m0, off, 64));
            m1 = fmaxf(m1, __shfl_xor(m1, off, 64));
        }
        float e0v = act ? __expf(l0 - m0) : 0.f;
        float e1v = act ? __expf(l1 - m1) : 0.f;
        s0 = e0v; s1 = e1v;
#pragma unroll
        for (int off = 32; off; off >>= 1) {
            s0 += __shfl_xor(s0, off, 64);
            s1 += __shfl_xor(s1, off, 64);
        }
        inv0 = 1.f / (s0 + 1e-16f); inv1 = 1.f / (s1 + 1e-16f);
        if (act) { float2 av; av.x = e0v * inv0; av.y = e1v * inv1; al2[el] = av; }
        gather4(deg, el, sl, e0v, e1v, inv0, inv1, ea, xb, lane, h0q, h1q, gA0, gA1);
    } else {
        float m0 = -FLTMAX, m1 = -FLTMAX;
        for (int j = beg + lane; j < end; j += 64) {
            float2 lg = lgs2[j];
            m0 = fmaxf(m0, lg.x); m1 = fmaxf(m1, lg.y);
        }
#pragma unroll
        for (int off = 32; off; off >>= 1) {
            m0 = fmaxf(m0, __shfl_xor(m0, off, 64));
            m1 = fmaxf(m1, __shfl_xor(m1, off, 64));
        }
        s0 = 0.f; s1 = 0.f;
        for (int j = beg + lane; j < end; j += 64) {
            float2 lg = lgs2[j];
            s0 += __expf(lg.x - m0); s1 += __expf(lg.y - m1);
        }
#pragma unroll
        for (int off = 32; off; off >>= 1) {
            s0 += __shfl_xor(s0, off, 64);
            s1 += __shfl_xor(s1, off, 64);
        }
        inv0 = 1.f / (s0 + 1e-16f); inv1 = 1.f / (s1 + 1e-16f);
        for (int cb0 = beg; cb0 < end; cb0 += 64) {
            int cdeg = min(64, end - cb0);
            int jl = cb0 + min(lane, cdeg - 1);
            int2 pe = perm2[jl];
            int el = pe.x, sl = pe.y;
            float2 lgl = lgs2[jl];
            bool act = lane < cdeg;
            float e0v = act ? __expf(lgl.x - m0) : 0.f;
            float e1v = act ? __expf(lgl.y - m1) : 0.f;
            if (act) { float2 av; av.x = e0v * inv0; av.y = e1v * inv1; al2[el] = av; }
            gather4(cdeg, el, sl, e0v, e1v, inv0, inv1, ea, xb, lane, h0q, h1q, gA0, gA1);
        }
    }

#pragma unroll
    for (int ccc = 0; ccc < 4; ++ccc) {
        h0q[ccc] += __shfl_xor(h0q[ccc], 16, 64);
        h0q[ccc] += __shfl_xor(h0q[ccc], 32, 64);
        h1q[ccc] += __shfl_xor(h1q[ccc], 16, 64);
        h1q[ccc] += __shfl_xor(h1q[ccc], 32, 64);
        gA0[ccc] += __shfl_xor(gA0[ccc], 32, 64);
        gA1[ccc] += __shfl_xor(gA1[ccc], 32, 64);
    }
    if (lane < 32) {
        f32x4 hv = (lane < 16) ? h0q : h1q;
        *reinterpret_cast<f32x4*>(hrow + ((lane >> 4) * ED) + (lane & 15) * 4) = hv;
    }
    f32x4 gsel = half ? gA1 : gA0;
    float sa = (half ? s1 * inv1 : s0 * inv0);
    f32x4 res;
#pragma unroll
    for (int cc = 0; cc < 4; ++cc) {
        float eb = ebias[(sub32 * 4 + cc) * 2 + half];
        res[cc] = gsel[cc] + eb * sa;
    }
    *reinterpret_cast<f32x4*>(orow + half * F + sub32 * 4) = res;
}

__global__ __launch_bounds__(512) void emb_gemm(const float* __restrict__ H,
                                                const float* __restrict__ W_e,
                                                float* __restrict__ out) {
    __shared__ float WeT[ED][F];
    for (int i = threadIdx.x; i < ED * F; i += 512) {
        int f = i & (F - 1), k = i >> 7;
        WeT[k][f] = W_e[(size_t)f * ED + k];
    }
    __syncthreads();
    int lane = threadIdx.x & 63, wid = threadIdx.x >> 6;
    const int R = NN * C;
    for (int row = blockIdx.x * 8 + wid; row < R; row += gridDim.x * 8) {
        float h = H[(size_t)row * ED + lane];
        float m0 = 0.f, m1 = 0.f;
#pragma unroll
        for (int k = 0; k < ED; ++k) {
            float hk = __shfl(h, k, 64);
            m0 = fmaf(hk, WeT[k][lane], m0);
            m1 = fmaf(hk, WeT[k][lane + 64], m1);
        }
        float* op = out + (size_t)row * F;
        op[lane] += m0;
        op[lane + 64] += m1;
    }
}

extern "C" void kernel_launch(void* const* d_in, const int* in_sizes, int n_in,
                              void* d_out, int out_size, void* d_ws, size_t ws_size,
                              hipStream_t stream) {
    const float* x      = (const float*)d_in[0];
    const int*   ei     = (const int*)d_in[1];
    const float* ea     = (const float*)d_in[2];
    const float* W_l    = (const float*)d_in[3];
    const float* cb     = (const float*)d_in[4];
    const float* att    = (const float*)d_in[5];
    const float* att_sc = (const float*)d_in[6];
    const float* W_e    = (const float*)d_in[7];
    const float* ebias  = (const float*)d_in[8];

    float* out = (float*)d_out;
    float* alpha_out = out + (size_t)NN * C * F;

    float* ws = (float*)d_ws;
    float* xb   = ws;                          // 6,400,000 floats
    float* lgs  = ws + 6400000;                // 1,000,000 floats (sorted logits)
    int* ibase  = (int*)(ws + 7400000);
    int* counts = ibase;                       // NN (becomes cursor)
    int* offs   = ibase + NN;                  // NN+1 -> pad to 100064
    int* bsum   = ibase + 100064;              // 64
    int* tgts   = ibase + 100128;              // NE
    int2* perm2 = (int2*)(ibase + 100128 + NE); // NE int2
    char* tail = (char*)(ibase + 100128 + NE + 2 * NE);
    tail = (char*)(((size_t)tail + 15) & ~(size_t)15);
    size_t head_bytes = (size_t)(tail - (char*)d_ws);
    size_t msg_bytes = (size_t)NE * F * 2;     // 128 MB
    bool use_msg = ws_size >= head_bytes + msg_bytes + 64;
    unsigned short* msg = (unsigned short*)tail;
    float* H = (float*)tail;

    hipMemsetAsync(counts, 0, NN * sizeof(int), stream);

    proj_mfma<<<782, 256, 0, stream>>>(x, W_l, xb);

    hist_kernel<<<(NE + 255) / 256, 256, 0, stream>>>(ei, counts);
    const int NB = (NN + 1023) / 1024; // 49
    scan1_kernel<<<NB, 1024, 0, stream>>>(counts, offs, bsum);
    scan2_kernel<<<1, 64, 0, stream>>>(bsum, NB);
    scan3_kernel<<<NB, 1024, 0, stream>>>(offs, bsum, counts); // counts = cursor
    scatter_kernel<<<(NE + 255) / 256, 256, 0, stream>>>(ei, counts, perm2, tgts);

    if (use_msg) {
        edge_logits_mfma<true><<<2048, 256, 0, stream>>>(perm2, tgts, ea, xb, W_e,
                                                         cb, att, att_sc, ebias,
                                                         lgs, msg);
        agg_msg<<<(NN + 7) / 8, 512, 0, stream>>>(offs, perm2, msg, ebias, lgs,
                                                  out, alpha_out);
    } else {
        edge_logits_mfma<false><<<2048, 256, 0, stream>>>(perm2, tgts, ea, xb, W_e,
                                                          cb, att, att_sc, ebias,
                                                          lgs, (unsigned short*)0);
        agg_fast<<<(NN + 7) / 8, 512, 0, stream>>>(offs, perm2, ea, xb, ebias, lgs,
                                                   out, alpha_out, H);
        emb_gemm<<<1024, 512, 0, stream>>>(H, W_e, out);
    }
}

// Round 12
// 297.438 us; speedup vs baseline: 1.0803x; 1.0803x over previous
//
#include <hip/hip_runtime.h>
#include <hip/hip_bf16.h>

#define NN 50000
#define NE 500000
#define F 128
#define K_IN 128
#define ED 64
#define C 2
#define NEG 0.2f
#define FLTMAX 3.402823466e38f

typedef __attribute__((ext_vector_type(8))) short short8;
typedef __attribute__((ext_vector_type(4))) float f32x4;

#define FMA4(acc, v, s) do { \
    acc[0] = fmaf((v)[0], (s), acc[0]); \
    acc[1] = fmaf((v)[1], (s), acc[1]); \
    acc[2] = fmaf((v)[2], (s), acc[2]); \
    acc[3] = fmaf((v)[3], (s), acc[3]); } while (0)

__device__ __forceinline__ short bf16r(float f) {
    unsigned u = __float_as_uint(f);
    unsigned r = (u + 0x7fffu + ((u >> 16) & 1u)) >> 16;
    return (short)r;
}

__device__ __forceinline__ short8 ldfrag(const float* base) {
    const float4* p = reinterpret_cast<const float4*>(base);
    float4 v0 = p[0], v1 = p[1];
    short8 r;
    r[0] = bf16r(v0.x); r[1] = bf16r(v0.y); r[2] = bf16r(v0.z); r[3] = bf16r(v0.w);
    r[4] = bf16r(v1.x); r[5] = bf16r(v1.y); r[6] = bf16r(v1.z); r[7] = bf16r(v1.w);
    return r;
}

// ---------------- projection via MFMA: xb = x @ W_l^T ----------------
__global__ __launch_bounds__(256) void proj_mfma(const float* __restrict__ x,
                                                 const float* __restrict__ W_l,
                                                 float* __restrict__ xb) {
    int lane = threadIdx.x & 63, wid = threadIdx.x >> 6;
    int grp = lane >> 4, col = lane & 15;
    int tile = blockIdx.x * 4 + wid;
    if (tile >= NN / 16) return;
    int n0 = tile * 16;

    f32x4 acc[8];
#pragma unroll
    for (int t = 0; t < 8; ++t) acc[t] = (f32x4){0.f, 0.f, 0.f, 0.f};

    const float* arow = x + (size_t)(n0 + col) * K_IN + grp * 8;
#pragma unroll
    for (int kt = 0; kt < 4; ++kt) {
        short8 a = ldfrag(arow + kt * 32);
#pragma unroll
        for (int t = 0; t < 8; ++t) {
            short8 b = ldfrag(W_l + (size_t)(t * 16 + col) * K_IN + kt * 32 + grp * 8);
            acc[t] = __builtin_amdgcn_mfma_f32_16x16x32_bf16(a, b, acc[t], 0, 0, 0);
        }
    }
#pragma unroll
    for (int j = 0; j < 4; ++j) {
        float* orow = xb + (size_t)(n0 + grp * 4 + j) * F + col;
#pragma unroll
        for (int t = 0; t < 8; ++t) orow[t * 16] = acc[t][j];
    }
}

// ---------------- CSR build ----------------
__global__ void hist_kernel(const int* __restrict__ ei, int* __restrict__ counts) {
    int e = blockIdx.x * blockDim.x + threadIdx.x;
    if (e < NE) atomicAdd(&counts[ei[NE + e]], 1);
}

__global__ __launch_bounds__(1024) void scan1_kernel(const int* __restrict__ counts,
                                                     int* __restrict__ offs,
                                                     int* __restrict__ bsum) {
    __shared__ int wsum[16];
    int i = blockIdx.x * 1024 + threadIdx.x;
    int lane = threadIdx.x & 63, w = threadIdx.x >> 6;
    int v = (i < NN) ? counts[i] : 0;
    int x = v;
#pragma unroll
    for (int off = 1; off < 64; off <<= 1) {
        int y = __shfl_up(x, off, 64);
        if (lane >= off) x += y;
    }
    if (lane == 63) wsum[w] = x;
    __syncthreads();
    if (w == 0 && lane < 16) {
        int t = wsum[lane];
#pragma unroll
        for (int off = 1; off < 16; off <<= 1) {
            int y = __shfl_up(t, off, 16);
            if (lane >= off) t += y;
        }
        wsum[lane] = t;
    }
    __syncthreads();
    int woff = (w == 0) ? 0 : wsum[w - 1];
    if (i < NN) offs[i] = woff + x - v;
    if (threadIdx.x == 1023) bsum[blockIdx.x] = woff + x;
}

__global__ void scan2_kernel(int* __restrict__ bsum, int nb) {
    int tid = threadIdx.x;
    int v = (tid < nb) ? bsum[tid] : 0;
    int x = v;
#pragma unroll
    for (int off = 1; off < 64; off <<= 1) {
        int y = __shfl_up(x, off, 64);
        if (tid >= off) x += y;
    }
    if (tid < nb) bsum[tid] = x - v;
}

__global__ __launch_bounds__(1024) void scan3_kernel(int* __restrict__ offs,
                                                     const int* __restrict__ bsum,
                                                     int* __restrict__ cursor) {
    int i = blockIdx.x * 1024 + threadIdx.x;
    if (i < NN) {
        int o = offs[i] + bsum[blockIdx.x];
        offs[i] = o;
        cursor[i] = o;
    }
    if (i == 0) offs[NN] = NE;
}

// perm2[p] = {edge, src}; tgts[p] = tgt; pos[e] = p
__global__ void scatter_kernel(const int* __restrict__ ei, int* __restrict__ cursor,
                               int2* __restrict__ perm2, int* __restrict__ tgts,
                               int* __restrict__ pos) {
    int e = blockIdx.x * blockDim.x + threadIdx.x;
    if (e < NE) {
        int src = ei[e];
        int tgt = ei[NE + e];
        int p = atomicAdd(&cursor[tgt], 1);
        int2 v; v.x = e; v.y = src;
        perm2[p] = v;
        tgts[p] = tgt;
        pos[e] = p;
    }
}

// ---------------- presort ea into sorted bf16 rows (scatter on WRITE side) ----------------
// 16 threads per edge: coalesced f32 read, scattered-contiguous 128B bf16 row write
__global__ __launch_bounds__(256) void presort_ea(const float* __restrict__ ea,
                                                  const int* __restrict__ pos,
                                                  unsigned short* __restrict__ ea_s) {
    int gid = blockIdx.x * 256 + threadIdx.x;
    int e = gid >> 4, c = gid & 15;
    if (e >= NE) return;
    float4 v = *reinterpret_cast<const float4*>(ea + (size_t)e * ED + c * 4);
    int p = pos[e];
    ushort4 o;
    o.x = (unsigned short)bf16r(v.x);
    o.y = (unsigned short)bf16r(v.y);
    o.z = (unsigned short)bf16r(v.z);
    o.w = (unsigned short)bf16r(v.w);
    *reinterpret_cast<ushort4*>(ea_s + (size_t)p * ED + c * 4) = o;
}

// ---------------- edge logits, sorted order ----------------
// MODE 2: A-frags sequential from ea_s (bf16), write msg
// MODE 1: A-frags gathered from ea (f32->bf16), write msg
// MODE 0: gathered, no msg
template<int MODE>
__global__ __launch_bounds__(256) void edge_logits_mfma(
    const int2* __restrict__ perm2, const int* __restrict__ tgts,
    const float* __restrict__ ea, const unsigned short* __restrict__ ea_s,
    const float* __restrict__ xb, const float* __restrict__ W_e,
    const float* __restrict__ cb, const float* __restrict__ att,
    const float* __restrict__ att_sc, const float* __restrict__ ebias,
    float* __restrict__ lgs, unsigned short* __restrict__ msg) {
    int lane = threadIdx.x & 63, wid = threadIdx.x >> 6;
    int grp = lane >> 4, col = lane & 15;

    short8 B[8][2];
#pragma unroll
    for (int t = 0; t < 8; ++t)
#pragma unroll
        for (int kt = 0; kt < 2; ++kt)
            B[t][kt] = ldfrag(W_e + (size_t)(t * 16 + col) * ED + kt * 32 + grp * 8);

    float attv[8], cbe0[8], cbe1[8];
#pragma unroll
    for (int t = 0; t < 8; ++t) {
        int f = t * 16 + col;
        attv[t] = att[f];
        cbe0[t] = cb[f] + ebias[f * 2];
        cbe1[t] = cb[F + f] + ebias[f * 2 + 1];
    }
    float as0 = att_sc[0], as1 = att_sc[1];
    float2* lgs2 = reinterpret_cast<float2*>(lgs);

    for (int tile = blockIdx.x * 4 + wid; tile < NE / 16; tile += gridDim.x * 4) {
        int p0 = tile * 16;
        int2 pe = perm2[p0 + col];       // coalesced sequential
        int srcv = pe.y;
        int tgtv = tgts[p0 + col];       // coalesced sequential
        short8 a0, a1;
        if (MODE == 2) {
            const unsigned short* arow = ea_s + (size_t)(p0 + col) * ED + grp * 8;
            a0 = *reinterpret_cast<const short8*>(arow);        // sequential 16B
            a1 = *reinterpret_cast<const short8*>(arow + 32);   // sequential 16B
        } else {
            const float* arow = ea + (size_t)pe.x * ED + grp * 8;  // scattered rows
            a0 = ldfrag(arow);
            a1 = ldfrag(arow + 32);
        }
        f32x4 acc[8];
#pragma unroll
        for (int t = 0; t < 8; ++t) acc[t] = (f32x4){0.f, 0.f, 0.f, 0.f};
#pragma unroll
        for (int t = 0; t < 8; ++t) {
            acc[t] = __builtin_amdgcn_mfma_f32_16x16x32_bf16(a0, B[t][0], acc[t], 0, 0, 0);
            acc[t] = __builtin_amdgcn_mfma_f32_16x16x32_bf16(a1, B[t][1], acc[t], 0, 0, 0);
        }
#pragma unroll
        for (int j = 0; j < 4; ++j) {
            int idx = grp * 4 + j;
            int src = __shfl(srcv, idx, 16);
            int tgt = __shfl(tgtv, idx, 16);  // ~uniform per tile (sorted)
            const float* xbs = xb + (size_t)src * F + col;
            const float* xbt = xb + (size_t)tgt * F + col;
            float q0 = 0.f, q1 = 0.f;
#pragma unroll
            for (int t = 0; t < 8; ++t) {
                float mv = xbs[t * 16] + acc[t][j];        // xj + emb
                if (MODE >= 1)
                    msg[(size_t)(p0 + idx) * F + t * 16 + col] = (unsigned short)bf16r(mv);
                float s = mv + xbt[t * 16];
                float u0 = s + cbe0[t]; u0 = fmaxf(u0, NEG * u0);
                float u1 = s + cbe1[t]; u1 = fmaxf(u1, NEG * u1);
                q0 = fmaf(u0, attv[t], q0);
                q1 = fmaf(u1, attv[t], q1);
            }
#pragma unroll
            for (int off = 8; off; off >>= 1) {
                q0 += __shfl_xor(q0, off, 16);
                q1 += __shfl_xor(q1, off, 16);
            }
            if (col == 0) {
                float2 o; o.x = q0 * as0; o.y = q1 * as1;
                lgs2[p0 + idx] = o;
            }
        }
    }
}

// ---------------- streaming aggregation from msg ----------------
__global__ __launch_bounds__(512) void agg_msg(
    const int* __restrict__ offs, const int2* __restrict__ perm2,
    const unsigned short* __restrict__ msg, const float* __restrict__ ebias,
    const float* __restrict__ lgs,
    float* __restrict__ out, float* __restrict__ alpha_out) {
    int lane = threadIdx.x & 63;
    int node = blockIdx.x * 8 + (threadIdx.x >> 6);
    if (node >= NN) return;
    int beg = offs[node], end = offs[node + 1];
    int deg = end - beg;
    float* orow = out + (size_t)node * (C * F);
    float2* orow2 = reinterpret_cast<float2*>(orow);
    if (deg == 0) {
        float2 z; z.x = 0.f; z.y = 0.f;
        orow2[lane] = z; orow2[64 + lane] = z;
        return;
    }
    const float2* lgs2 = reinterpret_cast<const float2*>(lgs);
    float2* al2 = reinterpret_cast<float2*>(alpha_out);

    float m0 = -FLTMAX, m1 = -FLTMAX;
    for (int j = beg + lane; j < end; j += 64) {
        float2 lg = lgs2[j];
        m0 = fmaxf(m0, lg.x); m1 = fmaxf(m1, lg.y);
    }
#pragma unroll
    for (int off = 32; off; off >>= 1) {
        m0 = fmaxf(m0, __shfl_xor(m0, off, 64));
        m1 = fmaxf(m1, __shfl_xor(m1, off, 64));
    }
    float su0 = 0.f, su1 = 0.f;
    for (int j = beg + lane; j < end; j += 64) {
        float2 lg = lgs2[j];
        su0 += __expf(lg.x - m0); su1 += __expf(lg.y - m1);
    }
#pragma unroll
    for (int off = 32; off; off >>= 1) {
        su0 += __shfl_xor(su0, off, 64);
        su1 += __shfl_xor(su1, off, 64);
    }
    float inv0 = 1.f / (su0 + 1e-16f), inv1 = 1.f / (su1 + 1e-16f);

    float g00 = 0.f, g01 = 0.f, g10 = 0.f, g11 = 0.f;
    for (int cb0 = beg; cb0 < end; cb0 += 64) {
        int cnt = min(64, end - cb0);
        int jl = cb0 + min(lane, cnt - 1);
        bool act = lane < cnt;
        int el = perm2[jl].x;
        float2 lgl = lgs2[jl];
        float e0v = act ? __expf(lgl.x - m0) : 0.f;
        float e1v = act ? __expf(lgl.y - m1) : 0.f;
        if (act) { float2 av; av.x = e0v * inv0; av.y = e1v * inv1; al2[el] = av; }
#pragma unroll 4
        for (int i = 0; i < cnt; ++i) {
            float a0 = __shfl(e0v, i, 64) * inv0;
            float a1 = __shfl(e1v, i, 64) * inv1;
            unsigned mv = *reinterpret_cast<const unsigned*>(
                msg + (size_t)(cb0 + i) * F + lane * 2);
            float f0 = __uint_as_float((mv & 0xffffu) << 16);
            float f1 = __uint_as_float(mv & 0xffff0000u);
            g00 = fmaf(a0, f0, g00); g01 = fmaf(a0, f1, g01);
            g10 = fmaf(a1, f0, g10); g11 = fmaf(a1, f1, g11);
        }
    }
    float sa0 = su0 * inv0, sa1 = su1 * inv1;
    int f0i = lane * 2, f1i = lane * 2 + 1;
    float2 r0, r1;
    r0.x = g00 + ebias[f0i * 2] * sa0;
    r0.y = g01 + ebias[f1i * 2] * sa0;
    r1.x = g10 + ebias[f0i * 2 + 1] * sa1;
    r1.y = g11 + ebias[f1i * 2 + 1] * sa1;
    orow2[lane] = r0;
    orow2[64 + lane] = r1;
}

// ---------------- fallback (r6 structure): gather4 agg + H + emb_gemm ----------------
__device__ __forceinline__ void gather4(int cdeg, int el, int sl, float e0v, float e1v,
                                        float inv0, float inv1,
                                        const float* __restrict__ ea,
                                        const float* __restrict__ xb, int lane,
                                        f32x4& h0q, f32x4& h1q, f32x4& g0, f32x4& g1) {
    int quad = lane >> 4, sub16 = lane & 15;
    int half = lane >> 5, sub32 = lane & 31;
    for (int jj = 0; jj < cdeg; jj += 4) {
        int idx = jj + quad;
        int cidx = min(idx, cdeg - 1);
        float w0 = (idx < cdeg) ? inv0 : 0.f;
        float w1 = (idx < cdeg) ? inv1 : 0.f;
        float a0q = __shfl(e0v, cidx, 64) * w0;
        float a1q = __shfl(e1v, cidx, 64) * w1;
        int eq = __shfl(el, cidx, 64);
        f32x4 ev = *reinterpret_cast<const f32x4*>(ea + (size_t)eq * ED + sub16 * 4);
        FMA4(h0q, ev, a0q); FMA4(h1q, ev, a1q);

        int idh = jj + half;
        int ch = min(idh, cdeg - 1);
        float b0 = (idh < cdeg) ? inv0 : 0.f;
        float b1 = (idh < cdeg) ? inv1 : 0.f;
        float aA0 = __shfl(e0v, ch, 64) * b0;
        float aA1 = __shfl(e1v, ch, 64) * b1;
        int sA = __shfl(sl, ch, 64);
        f32x4 xv = *reinterpret_cast<const f32x4*>(xb + (size_t)sA * F + sub32 * 4);
        FMA4(g0, xv, aA0); FMA4(g1, xv, aA1);

        int idh2 = jj + 2 + half;
        int ch2 = min(idh2, cdeg - 1);
        float c0 = (idh2 < cdeg) ? inv0 : 0.f;
        float c1 = (idh2 < cdeg) ? inv1 : 0.f;
        float aB0 = __shfl(e0v, ch2, 64) * c0;
        float aB1 = __shfl(e1v, ch2, 64) * c1;
        int sB = __shfl(sl, ch2, 64);
        f32x4 xv2 = *reinterpret_cast<const f32x4*>(xb + (size_t)sB * F + sub32 * 4);
        FMA4(g0, xv2, aB0); FMA4(g1, xv2, aB1);
    }
}

__global__ __launch_bounds__(512) void agg_fast(
    const int* __restrict__ offs, const int2* __restrict__ perm2,
    const float* __restrict__ ea, const float* __restrict__ xb,
    const float* __restrict__ ebias, const float* __restrict__ lgs,
    float* __restrict__ out, float* __restrict__ alpha_out,
    float* __restrict__ H) {
    int lane = threadIdx.x & 63;
    int node = blockIdx.x * 8 + (threadIdx.x >> 6);
    if (node >= NN) return;
    int beg = offs[node], end = offs[node + 1];
    int deg = end - beg;
    int half = lane >> 5, sub32 = lane & 31;
    float* orow = out + (size_t)node * (C * F);
    float* hrow = H + (size_t)node * (C * ED);

    if (deg == 0) {
        f32x4 z = (f32x4){0.f, 0.f, 0.f, 0.f};
        *reinterpret_cast<f32x4*>(orow + half * F + sub32 * 4) = z;
        if (lane < 32) *reinterpret_cast<f32x4*>(hrow + lane * 4) = z;
        return;
    }
    const float2* lgs2 = reinterpret_cast<const float2*>(lgs);
    float2* al2 = reinterpret_cast<float2*>(alpha_out);

    f32x4 h0q = (f32x4){0.f,0.f,0.f,0.f}, h1q = h0q, gA0 = h0q, gA1 = h0q;
    float s0, s1, inv0, inv1;

    if (deg <= 64) {
        int jl = beg + min(lane, deg - 1);
        int2 pe = perm2[jl];
        int el = pe.x, sl = pe.y;
        float2 lgl = lgs2[jl];
        bool act = lane < deg;
        float l0 = act ? lgl.x : -FLTMAX;
        float l1 = act ? lgl.y : -FLTMAX;
        float m0 = l0, m1 = l1;
#pragma unroll
        for (int off = 32; off; off >>= 1) {
            m0 = fmaxf(m0, __shfl_xor(m0, off, 64));
            m1 = fmaxf(m1, __shfl_xor(m1, off, 64));
        }
        float e0v = act ? __expf(l0 - m0) : 0.f;
        float e1v = act ? __expf(l1 - m1) : 0.f;
        s0 = e0v; s1 = e1v;
#pragma unroll
        for (int off = 32; off; off >>= 1) {
            s0 += __shfl_xor(s0, off, 64);
            s1 += __shfl_xor(s1, off, 64);
        }
        inv0 = 1.f / (s0 + 1e-16f); inv1 = 1.f / (s1 + 1e-16f);
        if (act) { float2 av; av.x = e0v * inv0; av.y = e1v * inv1; al2[el] = av; }
        gather4(deg, el, sl, e0v, e1v, inv0, inv1, ea, xb, lane, h0q, h1q, gA0, gA1);
    } else {
        float m0 = -FLTMAX, m1 = -FLTMAX;
        for (int j = beg + lane; j < end; j += 64) {
            float2 lg = lgs2[j];
            m0 = fmaxf(m0, lg.x); m1 = fmaxf(m1, lg.y);
        }
#pragma unroll
        for (int off = 32; off; off >>= 1) {
            m0 = fmaxf(m0, __shfl_xor(m0, off, 64));
            m1 = fmaxf(m1, __shfl_xor(m1, off, 64));
        }
        s0 = 0.f; s1 = 0.f;
        for (int j = beg + lane; j < end; j += 64) {
            float2 lg = lgs2[j];
            s0 += __expf(lg.x - m0); s1 += __expf(lg.y - m1);
        }
#pragma unroll
        for (int off = 32; off; off >>= 1) {
            s0 += __shfl_xor(s0, off, 64);
            s1 += __shfl_xor(s1, off, 64);
        }
        inv0 = 1.f / (s0 + 1e-16f); inv1 = 1.f / (s1 + 1e-16f);
        for (int cb0 = beg; cb0 < end; cb0 += 64) {
            int cdeg = min(64, end - cb0);
            int jl = cb0 + min(lane, cdeg - 1);
            int2 pe = perm2[jl];
            int el = pe.x, sl = pe.y;
            float2 lgl = lgs2[jl];
            bool act = lane < cdeg;
            float e0v = act ? __expf(lgl.x - m0) : 0.f;
            float e1v = act ? __expf(lgl.y - m1) : 0.f;
            if (act) { float2 av; av.x = e0v * inv0; av.y = e1v * inv1; al2[el] = av; }
            gather4(cdeg, el, sl, e0v, e1v, inv0, inv1, ea, xb, lane, h0q, h1q, gA0, gA1);
        }
    }

#pragma unroll
    for (int ccc = 0; ccc < 4; ++ccc) {
        h0q[ccc] += __shfl_xor(h0q[ccc], 16, 64);
        h0q[ccc] += __shfl_xor(h0q[ccc], 32, 64);
        h1q[ccc] += __shfl_xor(h1q[ccc], 16, 64);
        h1q[ccc] += __shfl_xor(h1q[ccc], 32, 64);
        gA0[ccc] += __shfl_xor(gA0[ccc], 32, 64);
        gA1[ccc] += __shfl_xor(gA1[ccc], 32, 64);
    }
    if (lane < 32) {
        f32x4 hv = (lane < 16) ? h0q : h1q;
        *reinterpret_cast<f32x4*>(hrow + ((lane >> 4) * ED) + (lane & 15) * 4) = hv;
    }
    f32x4 gsel = half ? gA1 : gA0;
    float sa = (half ? s1 * inv1 : s0 * inv0);
    f32x4 res;
#pragma unroll
    for (int cc = 0; cc < 4; ++cc) {
        float eb = ebias[(sub32 * 4 + cc) * 2 + half];
        res[cc] = gsel[cc] + eb * sa;
    }
    *reinterpret_cast<f32x4*>(orow + half * F + sub32 * 4) = res;
}

__global__ __launch_bounds__(512) void emb_gemm(const float* __restrict__ H,
                                                const float* __restrict__ W_e,
                                                float* __restrict__ out) {
    __shared__ float WeT[ED][F];
    for (int i = threadIdx.x; i < ED * F; i += 512) {
        int f = i & (F - 1), k = i >> 7;
        WeT[k][f] = W_e[(size_t)f * ED + k];
    }
    __syncthreads();
    int lane = threadIdx.x & 63, wid = threadIdx.x >> 6;
    const int R = NN * C;
    for (int row = blockIdx.x * 8 + wid; row < R; row += gridDim.x * 8) {
        float h = H[(size_t)row * ED + lane];
        float m0 = 0.f, m1 = 0.f;
#pragma unroll
        for (int k = 0; k < ED; ++k) {
            float hk = __shfl(h, k, 64);
            m0 = fmaf(hk, WeT[k][lane], m0);
            m1 = fmaf(hk, WeT[k][lane + 64], m1);
        }
        float* op = out + (size_t)row * F;
        op[lane] += m0;
        op[lane + 64] += m1;
    }
}

extern "C" void kernel_launch(void* const* d_in, const int* in_sizes, int n_in,
                              void* d_out, int out_size, void* d_ws, size_t ws_size,
                              hipStream_t stream) {
    const float* x      = (const float*)d_in[0];
    const int*   ei     = (const int*)d_in[1];
    const float* ea     = (const float*)d_in[2];
    const float* W_l    = (const float*)d_in[3];
    const float* cb     = (const float*)d_in[4];
    const float* att    = (const float*)d_in[5];
    const float* att_sc = (const float*)d_in[6];
    const float* W_e    = (const float*)d_in[7];
    const float* ebias  = (const float*)d_in[8];

    float* out = (float*)d_out;
    float* alpha_out = out + (size_t)NN * C * F;

    float* ws = (float*)d_ws;
    float* xb   = ws;                            // 25.6 MB
    float* lgs  = ws + 6400000;                  // 4 MB
    int* ibase  = (int*)(ws + 7400000);
    int* counts = ibase;                         // NN (becomes cursor)
    int* offs   = ibase + NN;                    // NN+1 (pad to 100064)
    int* bsum   = ibase + 100064;                // 64
    int* tgts   = ibase + 100128;                // NE
    int* pos    = ibase + 100128 + NE;           // NE
    int2* perm2 = (int2*)(ibase + 100128 + 2 * NE); // 2*NE ints
    char* tail = (char*)(ibase + 100128 + 4 * NE);
    tail = (char*)(((size_t)tail + 15) & ~(size_t)15);
    size_t head_bytes = (size_t)(tail - (char*)d_ws);
    size_t eas_bytes = (size_t)NE * ED * 2;      // 64 MB
    size_t msg_bytes = (size_t)NE * F * 2;       // 128 MB
    bool use_full = ws_size >= head_bytes + eas_bytes + msg_bytes + 64;
    bool use_msg  = ws_size >= head_bytes + msg_bytes + 64;

    unsigned short* ea_s = (unsigned short*)tail;
    unsigned short* msg  = use_full ? (unsigned short*)(tail + eas_bytes)
                                    : (unsigned short*)tail;
    float* H = (float*)tail;

    hipMemsetAsync(counts, 0, NN * sizeof(int), stream);

    proj_mfma<<<782, 256, 0, stream>>>(x, W_l, xb);

    hist_kernel<<<(NE + 255) / 256, 256, 0, stream>>>(ei, counts);
    const int NB = (NN + 1023) / 1024; // 49
    scan1_kernel<<<NB, 1024, 0, stream>>>(counts, offs, bsum);
    scan2_kernel<<<1, 64, 0, stream>>>(bsum, NB);
    scan3_kernel<<<NB, 1024, 0, stream>>>(offs, bsum, counts); // counts = cursor
    scatter_kernel<<<(NE + 255) / 256, 256, 0, stream>>>(ei, counts, perm2, tgts, pos);

    if (use_full) {
        presort_ea<<<(NE * 16 + 255) / 256, 256, 0, stream>>>(ea, pos, ea_s);
        edge_logits_mfma<2><<<2048, 256, 0, stream>>>(perm2, tgts, ea, ea_s, xb, W_e,
                                                      cb, att, att_sc, ebias, lgs, msg);
        agg_msg<<<(NN + 7) / 8, 512, 0, stream>>>(offs, perm2, msg, ebias, lgs,
                                                  out, alpha_out);
    } else if (use_msg) {
        edge_logits_mfma<1><<<2048, 256, 0, stream>>>(perm2, tgts, ea, ea_s, xb, W_e,
                                                      cb, att, att_sc, ebias, lgs, msg);
        agg_msg<<<(NN + 7) / 8, 512, 0, stream>>>(offs, perm2, msg, ebias, lgs,
                                                  out, alpha_out);
    } else {
        edge_logits_mfma<0><<<2048, 256, 0, stream>>>(perm2, tgts, ea, ea_s, xb, W_e,
                                                      cb, att, att_sc, ebias, lgs,
                                                      (unsigned short*)0);
        agg_fast<<<(NN + 7) / 8, 512, 0, stream>>>(offs, perm2, ea, xb, ebias, lgs,
                                                   out, alpha_out, H);
        emb_gemm<<<1024, 512, 0, stream>>>(H, W_e, out);
    }
}

// Round 13
// 276.535 us; speedup vs baseline: 1.1620x; 1.0756x over previous
//
#include <hip/hip_runtime.h>
#include <hip/hip_bf16.h>

#define NN 50000
#define NE 500000
#define F 128
#define K_IN 128
#define ED 64
#define C 2
#define NEG 0.2f
#define FLTMAX 3.402823466e38f

typedef __attribute__((ext_vector_type(8))) short short8;
typedef __attribute__((ext_vector_type(8))) unsigned short ushort8;
typedef __attribute__((ext_vector_type(4))) float f32x4;

__device__ __forceinline__ short bf16r(float f) {
    unsigned u = __float_as_uint(f);
    unsigned r = (u + 0x7fffu + ((u >> 16) & 1u)) >> 16;
    return (short)r;
}

__device__ __forceinline__ float b2f(unsigned short v) {
    return __uint_as_float(((unsigned)v) << 16);
}

__device__ __forceinline__ short8 ldfrag(const float* base) {
    const float4* p = reinterpret_cast<const float4*>(base);
    float4 v0 = p[0], v1 = p[1];
    short8 r;
    r[0] = bf16r(v0.x); r[1] = bf16r(v0.y); r[2] = bf16r(v0.z); r[3] = bf16r(v0.w);
    r[4] = bf16r(v1.x); r[5] = bf16r(v1.y); r[6] = bf16r(v1.z); r[7] = bf16r(v1.w);
    return r;
}

// packed xb layout: xbp[n*128 + col*8 + t] = bf16(x_base[n][t*16+col])
// ---------------- projection via MFMA: xbp = pack(x @ W_l^T) ----------------
__global__ __launch_bounds__(256) void proj_mfma(const float* __restrict__ x,
                                                 const float* __restrict__ W_l,
                                                 unsigned short* __restrict__ xbp) {
    int lane = threadIdx.x & 63, wid = threadIdx.x >> 6;
    int grp = lane >> 4, col = lane & 15;
    int tile = blockIdx.x * 4 + wid;
    if (tile >= NN / 16) return;
    int n0 = tile * 16;

    f32x4 acc[8];
#pragma unroll
    for (int t = 0; t < 8; ++t) acc[t] = (f32x4){0.f, 0.f, 0.f, 0.f};

    const float* arow = x + (size_t)(n0 + col) * K_IN + grp * 8;
#pragma unroll
    for (int kt = 0; kt < 4; ++kt) {
        short8 a = ldfrag(arow + kt * 32);
#pragma unroll
        for (int t = 0; t < 8; ++t) {
            short8 b = ldfrag(W_l + (size_t)(t * 16 + col) * K_IN + kt * 32 + grp * 8);
            acc[t] = __builtin_amdgcn_mfma_f32_16x16x32_bf16(a, b, acc[t], 0, 0, 0);
        }
    }
#pragma unroll
    for (int j = 0; j < 4; ++j) {
        ushort8 o;
#pragma unroll
        for (int t = 0; t < 8; ++t) o[t] = (unsigned short)bf16r(acc[t][j]);
        *reinterpret_cast<ushort8*>(xbp + (size_t)(n0 + grp * 4 + j) * F + col * 8) = o;
    }
}

// ---------------- CSR build ----------------
__global__ void hist_kernel(const int* __restrict__ ei, int* __restrict__ counts) {
    int e = blockIdx.x * blockDim.x + threadIdx.x;
    if (e < NE) atomicAdd(&counts[ei[NE + e]], 1);
}

__global__ __launch_bounds__(1024) void scan1_kernel(const int* __restrict__ counts,
                                                     int* __restrict__ offs,
                                                     int* __restrict__ bsum) {
    __shared__ int wsum[16];
    int i = blockIdx.x * 1024 + threadIdx.x;
    int lane = threadIdx.x & 63, w = threadIdx.x >> 6;
    int v = (i < NN) ? counts[i] : 0;
    int x = v;
#pragma unroll
    for (int off = 1; off < 64; off <<= 1) {
        int y = __shfl_up(x, off, 64);
        if (lane >= off) x += y;
    }
    if (lane == 63) wsum[w] = x;
    __syncthreads();
    if (w == 0 && lane < 16) {
        int t = wsum[lane];
#pragma unroll
        for (int off = 1; off < 16; off <<= 1) {
            int y = __shfl_up(t, off, 16);
            if (lane >= off) t += y;
        }
        wsum[lane] = t;
    }
    __syncthreads();
    int woff = (w == 0) ? 0 : wsum[w - 1];
    if (i < NN) offs[i] = woff + x - v;
    if (threadIdx.x == 1023) bsum[blockIdx.x] = woff + x;
}

__global__ void scan2_kernel(int* __restrict__ bsum, int nb) {
    int tid = threadIdx.x;
    int v = (tid < nb) ? bsum[tid] : 0;
    int x = v;
#pragma unroll
    for (int off = 1; off < 64; off <<= 1) {
        int y = __shfl_up(x, off, 64);
        if (tid >= off) x += y;
    }
    if (tid < nb) bsum[tid] = x - v;
}

__global__ __launch_bounds__(1024) void scan3_kernel(int* __restrict__ offs,
                                                     const int* __restrict__ bsum,
                                                     int* __restrict__ cursor) {
    int i = blockIdx.x * 1024 + threadIdx.x;
    if (i < NN) {
        int o = offs[i] + bsum[blockIdx.x];
        offs[i] = o;
        cursor[i] = o;
    }
    if (i == 0) offs[NN] = NE;
}

// perm2[p] = {edge, src}; tgts[p] = tgt
__global__ void scatter_kernel(const int* __restrict__ ei, int* __restrict__ cursor,
                               int2* __restrict__ perm2, int* __restrict__ tgts) {
    int e = blockIdx.x * blockDim.x + threadIdx.x;
    if (e < NE) {
        int src = ei[e];
        int tgt = ei[NE + e];
        int p = atomicAdd(&cursor[tgt], 1);
        int2 v; v.x = e; v.y = src;
        perm2[p] = v;
        tgts[p] = tgt;
    }
}

// ---------------- edge logits, sorted order, packed-bf16 xb ----------------
// MODE 1: write msg; MODE 0: no msg (fallback)
template<int MODE>
__global__ __launch_bounds__(256) void edge_logits_mfma(
    const int2* __restrict__ perm2, const int* __restrict__ tgts,
    const float* __restrict__ ea,
    const unsigned short* __restrict__ xbp, const float* __restrict__ W_e,
    const float* __restrict__ cb, const float* __restrict__ att,
    const float* __restrict__ att_sc, const float* __restrict__ ebias,
    float* __restrict__ lgs, unsigned short* __restrict__ msg) {
    int lane = threadIdx.x & 63, wid = threadIdx.x >> 6;
    int grp = lane >> 4, col = lane & 15;

    short8 B[8][2];
#pragma unroll
    for (int t = 0; t < 8; ++t)
#pragma unroll
        for (int kt = 0; kt < 2; ++kt)
            B[t][kt] = ldfrag(W_e + (size_t)(t * 16 + col) * ED + kt * 32 + grp * 8);

    float attv[8], cbe0[8], cbe1[8];
#pragma unroll
    for (int t = 0; t < 8; ++t) {
        int f = t * 16 + col;
        attv[t] = att[f];
        cbe0[t] = cb[f] + ebias[f * 2];
        cbe1[t] = cb[F + f] + ebias[f * 2 + 1];
    }
    float as0 = att_sc[0], as1 = att_sc[1];
    float2* lgs2 = reinterpret_cast<float2*>(lgs);

    for (int tile = blockIdx.x * 4 + wid; tile < NE / 16; tile += gridDim.x * 4) {
        int p0 = tile * 16;
        int2 pe = perm2[p0 + col];       // coalesced sequential
        int srcv = pe.y;
        int tgtv = tgts[p0 + col];       // coalesced sequential
        const float* arow = ea + (size_t)pe.x * ED + grp * 8;   // scattered rows
        short8 a0 = ldfrag(arow);
        short8 a1 = ldfrag(arow + 32);
        f32x4 acc[8];
#pragma unroll
        for (int t = 0; t < 8; ++t) acc[t] = (f32x4){0.f, 0.f, 0.f, 0.f};
#pragma unroll
        for (int t = 0; t < 8; ++t) {
            acc[t] = __builtin_amdgcn_mfma_f32_16x16x32_bf16(a0, B[t][0], acc[t], 0, 0, 0);
            acc[t] = __builtin_amdgcn_mfma_f32_16x16x32_bf16(a1, B[t][1], acc[t], 0, 0, 0);
        }
#pragma unroll
        for (int j = 0; j < 4; ++j) {
            int idx = grp * 4 + j;
            int src = __shfl(srcv, idx, 16);
            int tgt = __shfl(tgtv, idx, 16);  // ~uniform per tile (sorted)
            // one 16B packed row-fragment load each (8 f-values for this col)
            ushort8 xs = *reinterpret_cast<const ushort8*>(
                xbp + (size_t)src * F + col * 8);
            ushort8 xt = *reinterpret_cast<const ushort8*>(
                xbp + (size_t)tgt * F + col * 8);
            float q0 = 0.f, q1 = 0.f;
#pragma unroll
            for (int t = 0; t < 8; ++t) {
                float mv = b2f(xs[t]) + acc[t][j];        // xj + emb
                if (MODE >= 1)
                    msg[(size_t)(p0 + idx) * F + t * 16 + col] = (unsigned short)bf16r(mv);
                float s = mv + b2f(xt[t]);
                float u0 = s + cbe0[t]; u0 = fmaxf(u0, NEG * u0);
                float u1 = s + cbe1[t]; u1 = fmaxf(u1, NEG * u1);
                q0 = fmaf(u0, attv[t], q0);
                q1 = fmaf(u1, attv[t], q1);
            }
#pragma unroll
            for (int off = 8; off; off >>= 1) {
                q0 += __shfl_xor(q0, off, 16);
                q1 += __shfl_xor(q1, off, 16);
            }
            if (col == 0) {
                float2 o; o.x = q0 * as0; o.y = q1 * as1;
                lgs2[p0 + idx] = o;
            }
        }
    }
}

// ---------------- streaming aggregation from msg ----------------
__global__ __launch_bounds__(512) void agg_msg(
    const int* __restrict__ offs, const int2* __restrict__ perm2,
    const unsigned short* __restrict__ msg, const float* __restrict__ ebias,
    const float* __restrict__ lgs,
    float* __restrict__ out, float* __restrict__ alpha_out) {
    int lane = threadIdx.x & 63;
    int node = blockIdx.x * 8 + (threadIdx.x >> 6);
    if (node >= NN) return;
    int beg = offs[node], end = offs[node + 1];
    int deg = end - beg;
    float* orow = out + (size_t)node * (C * F);
    float2* orow2 = reinterpret_cast<float2*>(orow);
    if (deg == 0) {
        float2 z; z.x = 0.f; z.y = 0.f;
        orow2[lane] = z; orow2[64 + lane] = z;
        return;
    }
    const float2* lgs2 = reinterpret_cast<const float2*>(lgs);
    float2* al2 = reinterpret_cast<float2*>(alpha_out);

    float m0 = -FLTMAX, m1 = -FLTMAX;
    for (int j = beg + lane; j < end; j += 64) {
        float2 lg = lgs2[j];
        m0 = fmaxf(m0, lg.x); m1 = fmaxf(m1, lg.y);
    }
#pragma unroll
    for (int off = 32; off; off >>= 1) {
        m0 = fmaxf(m0, __shfl_xor(m0, off, 64));
        m1 = fmaxf(m1, __shfl_xor(m1, off, 64));
    }
    float su0 = 0.f, su1 = 0.f;
    for (int j = beg + lane; j < end; j += 64) {
        float2 lg = lgs2[j];
        su0 += __expf(lg.x - m0); su1 += __expf(lg.y - m1);
    }
#pragma unroll
    for (int off = 32; off; off >>= 1) {
        su0 += __shfl_xor(su0, off, 64);
        su1 += __shfl_xor(su1, off, 64);
    }
    float inv0 = 1.f / (su0 + 1e-16f), inv1 = 1.f / (su1 + 1e-16f);

    float g00 = 0.f, g01 = 0.f, g10 = 0.f, g11 = 0.f;
    for (int cb0 = beg; cb0 < end; cb0 += 64) {
        int cnt = min(64, end - cb0);
        int jl = cb0 + min(lane, cnt - 1);
        bool act = lane < cnt;
        int el = perm2[jl].x;
        float2 lgl = lgs2[jl];
        float e0v = act ? __expf(lgl.x - m0) : 0.f;
        float e1v = act ? __expf(lgl.y - m1) : 0.f;
        if (act) { float2 av; av.x = e0v * inv0; av.y = e1v * inv1; al2[el] = av; }
#pragma unroll 4
        for (int i = 0; i < cnt; ++i) {
            float a0 = __shfl(e0v, i, 64) * inv0;
            float a1 = __shfl(e1v, i, 64) * inv1;
            unsigned mv = *reinterpret_cast<const unsigned*>(
                msg + (size_t)(cb0 + i) * F + lane * 2);
            float f0 = __uint_as_float((mv & 0xffffu) << 16);
            float f1 = __uint_as_float(mv & 0xffff0000u);
            g00 = fmaf(a0, f0, g00); g01 = fmaf(a0, f1, g01);
            g10 = fmaf(a1, f0, g10); g11 = fmaf(a1, f1, g11);
        }
    }
    float sa0 = su0 * inv0, sa1 = su1 * inv1;
    int f0i = lane * 2, f1i = lane * 2 + 1;
    float2 r0, r1;
    r0.x = g00 + ebias[f0i * 2] * sa0;
    r0.y = g01 + ebias[f1i * 2] * sa0;
    r1.x = g10 + ebias[f0i * 2 + 1] * sa1;
    r1.y = g11 + ebias[f1i * 2 + 1] * sa1;
    orow2[lane] = r0;
    orow2[64 + lane] = r1;
}

// ---------------- fallback (never expected to run): gather agg + H + emb_gemm ----------------
__device__ __forceinline__ float xbval(const unsigned short* __restrict__ xbp,
                                       int n, int f) {
    return b2f(xbp[(size_t)n * F + (f & 15) * 8 + (f >> 4)]);
}

__global__ __launch_bounds__(512) void agg_fast(
    const int* __restrict__ offs, const int2* __restrict__ perm2,
    const float* __restrict__ ea, const unsigned short* __restrict__ xbp,
    const float* __restrict__ ebias, const float* __restrict__ lgs,
    float* __restrict__ out, float* __restrict__ alpha_out,
    float* __restrict__ H) {
    int lane = threadIdx.x & 63;
    int node = blockIdx.x * 8 + (threadIdx.x >> 6);
    if (node >= NN) return;
    int beg = offs[node], end = offs[node + 1];
    int deg = end - beg;
    float* orow = out + (size_t)node * (C * F);
    float* hrow = H + (size_t)node * (C * ED);

    if (deg == 0) {
        orow[lane] = 0.f; orow[64 + lane] = 0.f;
        orow[128 + lane] = 0.f; orow[192 + lane] = 0.f;
        if (lane < 32) { hrow[lane * 4] = 0.f; hrow[lane * 4 + 1] = 0.f;
                         hrow[lane * 4 + 2] = 0.f; hrow[lane * 4 + 3] = 0.f; }
        return;
    }
    const float2* lgs2 = reinterpret_cast<const float2*>(lgs);
    float2* al2 = reinterpret_cast<float2*>(alpha_out);

    float m0 = -FLTMAX, m1 = -FLTMAX;
    for (int j = beg + lane; j < end; j += 64) {
        float2 lg = lgs2[j];
        m0 = fmaxf(m0, lg.x); m1 = fmaxf(m1, lg.y);
    }
#pragma unroll
    for (int off = 32; off; off >>= 1) {
        m0 = fmaxf(m0, __shfl_xor(m0, off, 64));
        m1 = fmaxf(m1, __shfl_xor(m1, off, 64));
    }
    float s0 = 0.f, s1 = 0.f;
    for (int j = beg + lane; j < end; j += 64) {
        float2 lg = lgs2[j];
        s0 += __expf(lg.x - m0); s1 += __expf(lg.y - m1);
    }
#pragma unroll
    for (int off = 32; off; off >>= 1) {
        s0 += __shfl_xor(s0, off, 64);
        s1 += __shfl_xor(s1, off, 64);
    }
    float inv0 = 1.f / (s0 + 1e-16f), inv1 = 1.f / (s1 + 1e-16f);

    float h0 = 0.f, h1 = 0.f;
    float g00 = 0.f, g01 = 0.f, g10 = 0.f, g11 = 0.f;
    for (int j = beg; j < end; ++j) {
        int2 pe; pe.x = __builtin_amdgcn_readfirstlane(perm2[j].x);
        pe.y = __builtin_amdgcn_readfirstlane(perm2[j].y);
        float2 lg = lgs2[j];
        float a0 = __builtin_amdgcn_readfirstlane(__expf(lg.x - m0)) * inv0;
        float a1 = __builtin_amdgcn_readfirstlane(__expf(lg.y - m1)) * inv1;
        if (lane == 0) { float2 av; av.x = a0; av.y = a1; al2[pe.x] = av; }
        float av = ea[(size_t)pe.x * ED + lane];
        h0 = fmaf(a0, av, h0); h1 = fmaf(a1, av, h1);
        float xv0 = xbval(xbp, pe.y, lane);
        float xv1 = xbval(xbp, pe.y, 64 + lane);
        g00 = fmaf(a0, xv0, g00); g01 = fmaf(a1, xv0, g01);
        g10 = fmaf(a0, xv1, g10); g11 = fmaf(a1, xv1, g11);
    }
    hrow[lane] = h0; hrow[64 + lane] = h1;
    float sa0 = s0 * inv0, sa1 = s1 * inv1;
    orow[lane]       = g00 + ebias[lane * 2] * sa0;
    orow[64 + lane]  = g10 + ebias[(64 + lane) * 2] * sa0;
    orow[128 + lane] = g01 + ebias[lane * 2 + 1] * sa1;
    orow[192 + lane] = g11 + ebias[(64 + lane) * 2 + 1] * sa1;
}

__global__ __launch_bounds__(512) void emb_gemm(const float* __restrict__ H,
                                                const float* __restrict__ W_e,
                                                float* __restrict__ out) {
    __shared__ float WeT[ED][F];
    for (int i = threadIdx.x; i < ED * F; i += 512) {
        int f = i & (F - 1), k = i >> 7;
        WeT[k][f] = W_e[(size_t)f * ED + k];
    }
    __syncthreads();
    int lane = threadIdx.x & 63, wid = threadIdx.x >> 6;
    const int R = NN * C;
    for (int row = blockIdx.x * 8 + wid; row < R; row += gridDim.x * 8) {
        float h = H[(size_t)row * ED + lane];
        float m0 = 0.f, m1 = 0.f;
#pragma unroll
        for (int k = 0; k < ED; ++k) {
            float hk = __shfl(h, k, 64);
            m0 = fmaf(hk, WeT[k][lane], m0);
            m1 = fmaf(hk, WeT[k][lane + 64], m1);
        }
        float* op = out + (size_t)row * F;
        op[lane] += m0;
        op[lane + 64] += m1;
    }
}

extern "C" void kernel_launch(void* const* d_in, const int* in_sizes, int n_in,
                              void* d_out, int out_size, void* d_ws, size_t ws_size,
                              hipStream_t stream) {
    const float* x      = (const float*)d_in[0];
    const int*   ei     = (const int*)d_in[1];
    const float* ea     = (const float*)d_in[2];
    const float* W_l    = (const float*)d_in[3];
    const float* cb     = (const float*)d_in[4];
    const float* att    = (const float*)d_in[5];
    const float* att_sc = (const float*)d_in[6];
    const float* W_e    = (const float*)d_in[7];
    const float* ebias  = (const float*)d_in[8];

    float* out = (float*)d_out;
    float* alpha_out = out + (size_t)NN * C * F;

    float* ws = (float*)d_ws;
    unsigned short* xbp = (unsigned short*)ws;   // 12.8 MB (region reserves 25.6)
    float* lgs  = ws + 6400000;                  // 4 MB
    int* ibase  = (int*)(ws + 7400000);
    int* counts = ibase;                         // NN (becomes cursor)
    int* offs   = ibase + NN;                    // NN+1 (pad to 100064)
    int* bsum   = ibase + 100064;                // 64
    int* tgts   = ibase + 100128;                // NE
    int2* perm2 = (int2*)(ibase + 100128 + NE);  // NE int2
    char* tail = (char*)(ibase + 100128 + 3 * NE);
    tail = (char*)(((size_t)tail + 15) & ~(size_t)15);
    size_t head_bytes = (size_t)(tail - (char*)d_ws);
    size_t msg_bytes = (size_t)NE * F * 2;       // 128 MB
    bool use_msg = ws_size >= head_bytes + msg_bytes + 64;
    unsigned short* msg = (unsigned short*)tail;
    float* H = (float*)tail;

    hipMemsetAsync(counts, 0, NN * sizeof(int), stream);

    proj_mfma<<<782, 256, 0, stream>>>(x, W_l, xbp);

    hist_kernel<<<(NE + 255) / 256, 256, 0, stream>>>(ei, counts);
    const int NB = (NN + 1023) / 1024; // 49
    scan1_kernel<<<NB, 1024, 0, stream>>>(counts, offs, bsum);
    scan2_kernel<<<1, 64, 0, stream>>>(bsum, NB);
    scan3_kernel<<<NB, 1024, 0, stream>>>(offs, bsum, counts); // counts = cursor
    scatter_kernel<<<(NE + 255) / 256, 256, 0, stream>>>(ei, counts, perm2, tgts);

    if (use_msg) {
        edge_logits_mfma<1><<<2048, 256, 0, stream>>>(perm2, tgts, ea, xbp, W_e,
                                                      cb, att, att_sc, ebias,
                                                      lgs, msg);
        agg_msg<<<(NN + 7) / 8, 512, 0, stream>>>(offs, perm2, msg, ebias, lgs,
                                                  out, alpha_out);
    } else {
        edge_logits_mfma<0><<<2048, 256, 0, stream>>>(perm2, tgts, ea, xbp, W_e,
                                                      cb, att, att_sc, ebias,
                                                      lgs, (unsigned short*)0);
        agg_fast<<<(NN + 7) / 8, 512, 0, stream>>>(offs, perm2, ea, xbp, ebias, lgs,
                                                   out, alpha_out, H);
        emb_gemm<<<1024, 512, 0, stream>>>(H, W_e, out);
    }
}